// Round 7
// baseline (1397.767 us; speedup 1.0000x reference)
//
#include <hip/hip_runtime.h>
#include <hip/hip_bf16.h>
#include <math.h>

typedef __bf16 bf16x8 __attribute__((ext_vector_type(8)));
typedef float  f32x4  __attribute__((ext_vector_type(4)));

#define GAS(p) ((const __attribute__((address_space(1))) void*)(p))
#define LAS(p) ((__attribute__((address_space(3))) void*)(p))

static constexpr int NE = 768;

// ---------------- embed: x = tok_emb[idx] + pos_emb, -> bf16 ----------------
__global__ __launch_bounds__(256) void k_embed(const int* __restrict__ idx,
    const float* __restrict__ tok, const float* __restrict__ pos,
    __hip_bfloat16* __restrict__ xb)
{
    int bt = blockIdx.x;            // 0..8191
    int t  = bt & 2047;
    int token = idx[bt];
    const float* te = tok + (size_t)token * NE;
    const float* pe = pos + (size_t)t * NE;
    __hip_bfloat16* o = xb + (size_t)bt * NE;
    for (int c = threadIdx.x; c < NE; c += 256)
        o[c] = __float2bfloat16(te[c] + pe[c]);
}

// ------------- transpose fp32 [R][C] -> bf16 [outRows][R] (zero-pad) -------------
__global__ __launch_bounds__(256) void k_transpose_f32_bf16(
    const float* __restrict__ in, __hip_bfloat16* __restrict__ out,
    int R, int C, int outRows)
{
    __shared__ float tile[32][33];
    int c0 = blockIdx.x * 32, r0 = blockIdx.y * 32;
    int tx = threadIdx.x & 31, ty = threadIdx.x >> 5;
    #pragma unroll
    for (int i = 0; i < 32; i += 8) {
        int r = r0 + ty + i, c = c0 + tx;
        tile[ty + i][tx] = (r < R && c < C) ? in[(size_t)r * C + c] : 0.f;
    }
    __syncthreads();
    #pragma unroll
    for (int i = 0; i < 32; i += 8) {
        int oc = c0 + ty + i, orr = r0 + tx;
        if (oc < outRows && orr < R)
            out[(size_t)oc * R + orr] = __float2bfloat16(tile[tx][ty + i]);
    }
}

// ------------- batched bf16 transpose: in [z][R][C] -> out [z][C][R] -------------
__global__ __launch_bounds__(256) void k_transpose_bf16(
    const __hip_bfloat16* __restrict__ in, __hip_bfloat16* __restrict__ out,
    int R, int C)
{
    __shared__ __hip_bfloat16 tile[32][33];
    size_t boff = (size_t)blockIdx.z * R * C;
    int c0 = blockIdx.x * 32, r0 = blockIdx.y * 32;
    int tx = threadIdx.x & 31, ty = threadIdx.x >> 5;
    #pragma unroll
    for (int i = 0; i < 32; i += 8)
        tile[ty + i][tx] = in[boff + (size_t)(r0 + ty + i) * C + (c0 + tx)];
    __syncthreads();
    #pragma unroll
    for (int i = 0; i < 32; i += 8)
        out[boff + (size_t)(c0 + ty + i) * R + (r0 + tx)] = tile[tx][ty + i];
}

__global__ __launch_bounds__(256) void k_pack_bias(const float* __restrict__ bq,
    const float* __restrict__ bk, const float* __restrict__ bv, float* __restrict__ o)
{
    int i = blockIdx.x * 256 + threadIdx.x;
    if (i < 768) o[i] = bq[i];
    else if (i < 1536) o[i] = bk[i - 768];
    else if (i < 2304) o[i] = bv[i - 1536];
}

// ---------------- m97-style 128x128 bf16 MFMA GEMM (qkv/att/PV) ----------------
// MODE 0: qkv (bf16 out split q/k/v, +bias); MODE 1: att (fp32*scale, causal tile skip);
// MODE 2: PV (fp32 out, K truncated to (bm+1)*128; bm reversed so longest blocks start first)
template<int MODE>
__global__ __launch_bounds__(256) void k_gemm(
    const __hip_bfloat16* __restrict__ A, const __hip_bfloat16* __restrict__ Bt,
    int K, int lda, int ldb,
    size_t strideA, size_t strideB, size_t strideC,
    float* __restrict__ outf, int ldc, int ncols,
    const float* __restrict__ bias, float scale,
    __hip_bfloat16* __restrict__ oq, __hip_bfloat16* __restrict__ ok,
    __hip_bfloat16* __restrict__ ov)
{
    int bn = blockIdx.x, bm = blockIdx.y, bz = blockIdx.z;
    if constexpr (MODE == 2) bm = (int)gridDim.y - 1 - bm;   // longest-first dispatch
    if (MODE == 1 && bn > bm) return;   // fully masked causal tile
    __shared__ __align__(16) __hip_bfloat16 As[128 * 32];
    __shared__ __align__(16) __hip_bfloat16 Bs[128 * 32];
    const __hip_bfloat16* Ab = A  + bz * strideA + (size_t)bm * 128 * lda;
    const __hip_bfloat16* Bb = Bt + bz * strideB + (size_t)bn * 128 * ldb;
    int tid = threadIdx.x, w = tid >> 6, lane = tid & 63;
    int wr = w >> 1, wc = w & 1;
    f32x4 acc[4][4] = {};
    int sr = tid >> 2, sc = (tid & 3) * 8;
    int lr = lane & 15, lk = (lane >> 4) * 8;

    const int kend = (MODE == 2) ? (bm + 1) * 128 : K;   // causal K-truncation for PV

    for (int k0 = 0; k0 < kend; k0 += 32) {
        __syncthreads();
        #pragma unroll
        for (int i = 0; i < 2; ++i) {
            __builtin_amdgcn_global_load_lds(GAS(Ab + (size_t)(i * 64 + sr) * lda + k0 + sc),
                                             LAS((char*)As + i * 4096 + w * 1024), 16, 0, 0);
            __builtin_amdgcn_global_load_lds(GAS(Bb + (size_t)(i * 64 + sr) * ldb + k0 + sc),
                                             LAS((char*)Bs + i * 4096 + w * 1024), 16, 0, 0);
        }
        __syncthreads();
        bf16x8 af[4], bfv[4];
        #pragma unroll
        for (int mi = 0; mi < 4; ++mi)
            af[mi] = *(const bf16x8*)(As + (wr * 64 + mi * 16 + lr) * 32 + lk);
        #pragma unroll
        for (int ni = 0; ni < 4; ++ni)
            bfv[ni] = *(const bf16x8*)(Bs + (wc * 64 + ni * 16 + lr) * 32 + lk);
        #pragma unroll
        for (int mi = 0; mi < 4; ++mi)
            #pragma unroll
            for (int ni = 0; ni < 4; ++ni)
                acc[mi][ni] = __builtin_amdgcn_mfma_f32_16x16x32_bf16(af[mi], bfv[ni], acc[mi][ni], 0, 0, 0);
    }

    int r4 = (lane >> 4) * 4;
    #pragma unroll
    for (int mi = 0; mi < 4; ++mi) {
        #pragma unroll
        for (int ni = 0; ni < 4; ++ni) {
            #pragma unroll
            for (int r = 0; r < 4; ++r) {
                int row = bm * 128 + wr * 64 + mi * 16 + r4 + r;
                int col = bn * 128 + wc * 64 + ni * 16 + lr;
                float v = acc[mi][ni][r];
                if constexpr (MODE == 0) {
                    v += bias[col];
                    __hip_bfloat16 h = __float2bfloat16(v);
                    if (col < 768)       oq[(size_t)row * 768 + col]          = h;
                    else if (col < 1536) ok[(size_t)row * 768 + (col - 768)]  = h;
                    else                 ov[(size_t)row * 768 + (col - 1536)] = h;
                } else if constexpr (MODE == 1) {
                    outf[bz * strideC + (size_t)row * ldc + col] = v * scale;
                } else {
                    outf[bz * strideC + (size_t)row * ldc + col] = v;
                }
            }
        }
    }
}

// ================= 256x256 8-wave pipelined head GEMM (measured-1020 schedule) =================
// Changes vs measured-1020: (1) grid swapped to bm-fastest (x=32), bn slow (y=197),
// no swizzle — consecutive blocks share one B-panel so only ~8 B-panels are live
// chip-wide (R3-validated: FETCH 1.34GB -> 0.46GB). (2) QUAD MFMA order: all-k0
// across the 8 accs then all-k1 (dependency distance 8 instead of 1).
__global__ __launch_bounds__(512, 2) void k_gemm_head(
    const __hip_bfloat16* __restrict__ A,   // [8192][768]
    const __hip_bfloat16* __restrict__ Bt,  // [50432][768]
    float* __restrict__ out, const float* __restrict__ bias, int ldc, int ncols)
{
    constexpr int K = 768, NT = K / 64;     // 12 K-tiles
    __shared__ __align__(16) __hip_bfloat16 As[2][256 * 64];
    __shared__ __align__(16) __hip_bfloat16 Bs[2][256 * 64];

    const int bm = blockIdx.x, bn = blockIdx.y;   // bm fastest -> B-panel reuse
    const int tid = threadIdx.x;
    const int w = tid >> 6, lane = tid & 63;
    const int wr = w >> 2, wc = w & 3;          // wave tile: rows wr*128, cols wc*64
    const int lr = lane & 15, lu = lane >> 4;   // fragment lane mapping
    const int rswz = lr & 7;                    // row-driven XOR for 16B units

    const int srow = tid >> 3;                  // row within 64-row chunk
    const int sunit = (tid & 7) ^ (srow & 7);   // pre-swizzled source 16B unit
    const size_t Abase = (size_t)bm * 256 * K;
    const size_t Bbase = (size_t)bn * 256 * K;

    auto stageA = [&](int kt, int c, int p) {
        const __hip_bfloat16* src = A + Abase + (size_t)(c * 64 + srow) * K + kt * 64 + sunit * 8;
        __builtin_amdgcn_global_load_lds(GAS(src), LAS(&As[p][c * 4096 + tid * 8]), 16, 0, 0);
    };
    auto stageB = [&](int kt, int c, int p) {
        const __hip_bfloat16* src = Bt + Bbase + (size_t)(c * 64 + srow) * K + kt * 64 + sunit * 8;
        __builtin_amdgcn_global_load_lds(GAS(src), LAS(&Bs[p][c * 4096 + tid * 8]), 16, 0, 0);
    };
    auto rdA = [&](int p, int m, int kk) {
        return *(const bf16x8*)&As[p][(wr * 128 + m * 16 + lr) * 64 + ((kk * 4 + lu) ^ rswz) * 8];
    };
    auto rdB = [&](int p, int n, int kk) {
        return *(const bf16x8*)&Bs[p][(wc * 64 + n * 16 + lr) * 64 + ((kk * 4 + lu) ^ rswz) * 8];
    };

    f32x4 acc[8][4] = {};

    // prologue: tile 0 complete (buf 0); tile 1 B + A-lo (buf 1)
    stageB(0, 0, 0); stageB(0, 1, 0); stageB(0, 2, 0); stageB(0, 3, 0);
    stageA(0, 0, 0); stageA(0, 1, 0); stageA(0, 2, 0); stageA(0, 3, 0);
    stageB(1, 0, 1); stageB(1, 1, 1); stageB(1, 2, 1); stageB(1, 3, 1);
    stageA(1, 0, 1); stageA(1, 2, 1);

#define QUAD(Q)                                                                                          \
    {   bf16x8 a00 = rdA(p, 2*(Q),     0), a01 = rdA(p, 2*(Q),     1);                                   \
        bf16x8 a10 = rdA(p, 2*(Q) + 1, 0), a11 = rdA(p, 2*(Q) + 1, 1);                                   \
        __builtin_amdgcn_s_setprio(1);                                                                   \
        _Pragma("unroll")                                                                                \
        for (int n = 0; n < 4; ++n) {                                                                    \
            acc[2*(Q)][n]     = __builtin_amdgcn_mfma_f32_16x16x32_bf16(a00, bf[n][0], acc[2*(Q)][n],     0, 0, 0); \
            acc[2*(Q) + 1][n] = __builtin_amdgcn_mfma_f32_16x16x32_bf16(a10, bf[n][0], acc[2*(Q) + 1][n], 0, 0, 0); \
        }                                                                                                \
        _Pragma("unroll")                                                                                \
        for (int n = 0; n < 4; ++n) {                                                                    \
            acc[2*(Q)][n]     = __builtin_amdgcn_mfma_f32_16x16x32_bf16(a01, bf[n][1], acc[2*(Q)][n],     0, 0, 0); \
            acc[2*(Q) + 1][n] = __builtin_amdgcn_mfma_f32_16x16x32_bf16(a11, bf[n][1], acc[2*(Q) + 1][n], 0, 0, 0); \
        }                                                                                                \
        __builtin_amdgcn_s_setprio(0); }

    for (int kt = 0; kt < NT; ++kt) {
        const int p = kt & 1, pn = p ^ 1;
        // ---- phase 0: finish tile kt+1's staging (A-hi), wait tile kt landed, quadrant 0 + all B ----
        if (kt + 1 < NT) {
            stageA(kt + 1, 1, pn); stageA(kt + 1, 3, pn);
            asm volatile("s_waitcnt vmcnt(8)" ::: "memory");
        } else {
            asm volatile("s_waitcnt vmcnt(0)" ::: "memory");
        }
        asm volatile("s_barrier" ::: "memory");
        bf16x8 bf[4][2];
        #pragma unroll
        for (int n = 0; n < 4; ++n) { bf[n][0] = rdB(p, n, 0); bf[n][1] = rdB(p, n, 1); }
        QUAD(0)
        asm volatile("s_barrier" ::: "memory");
        // ---- phase 1: stage B-lo of kt+2 (B freed at phase 0), quadrant 1 ----
        if (kt + 2 < NT) { stageB(kt + 2, 0, p); stageB(kt + 2, 1, p); }
        QUAD(1)
        asm volatile("s_barrier" ::: "memory");
        // ---- phase 2: stage B-hi of kt+2, quadrant 2 ----
        if (kt + 2 < NT) { stageB(kt + 2, 2, p); stageB(kt + 2, 3, p); }
        QUAD(2)
        asm volatile("s_barrier" ::: "memory");
        // ---- phase 3: stage A chunks 0,2 of kt+2 (rows freed at phase 1), quadrant 3 ----
        if (kt + 2 < NT) { stageA(kt + 2, 0, p); stageA(kt + 2, 2, p); }
        QUAD(3)
        asm volatile("s_barrier" ::: "memory");
    }
#undef QUAD

    // epilogue: C-write with bias, col-bounded
    const int r4 = lu * 4;
    #pragma unroll
    for (int m = 0; m < 8; ++m) {
        #pragma unroll
        for (int n = 0; n < 4; ++n) {
            int col = bn * 256 + wc * 64 + n * 16 + lr;
            if (col < ncols) {
                float bv_ = bias[col];
                #pragma unroll
                for (int r = 0; r < 4; ++r) {
                    int row = bm * 256 + wr * 128 + m * 16 + r4 + r;
                    out[(size_t)row * ldc + col] = acc[m][n][r] + bv_;
                }
            }
        }
    }
}

// ---------------- causal softmax: float4 loads, __expf, zero-fill to 128-boundary ----------------
__global__ __launch_bounds__(256) void k_softmax(const float* __restrict__ att,
    __hip_bfloat16* __restrict__ P, int T)
{
    int t = blockIdx.x, b = blockIdx.y;
    const float* row = att + ((size_t)b * T + t) * T;
    __hip_bfloat16* prow = P + ((size_t)b * T + t) * T;
    const int n = t + 1;
    const int nz = ((t >> 7) + 1) << 7;     // PV (truncated) reads only cols < nz
    __shared__ float red[256];
    float4 v[2];
    float mx = -1e30f;
    #pragma unroll
    for (int j = 0; j < 2; ++j) {
        int e = (threadIdx.x + j * 256) * 4;
        v[j] = *(const float4*)(row + e);
        #pragma unroll
        for (int k = 0; k < 4; ++k)
            if (e + k < n) mx = fmaxf(mx, ((const float*)&v[j])[k]);
    }
    red[threadIdx.x] = mx; __syncthreads();
    for (int o = 128; o > 0; o >>= 1) {
        if (threadIdx.x < o) red[threadIdx.x] = fmaxf(red[threadIdx.x], red[threadIdx.x + o]);
        __syncthreads();
    }
    mx = red[0]; __syncthreads();
    float ev[8];
    float sum = 0.f;
    #pragma unroll
    for (int j = 0; j < 2; ++j) {
        int e = (threadIdx.x + j * 256) * 4;
        #pragma unroll
        for (int k = 0; k < 4; ++k) {
            float x = ((const float*)&v[j])[k];
            float ex = (e + k < n) ? __expf(x - mx) : 0.f;
            ev[j * 4 + k] = ex;
            sum += ex;
        }
    }
    red[threadIdx.x] = sum; __syncthreads();
    for (int o = 128; o > 0; o >>= 1) {
        if (threadIdx.x < o) red[threadIdx.x] += red[threadIdx.x + o];
        __syncthreads();
    }
    float inv = 1.f / red[0];
    #pragma unroll
    for (int j = 0; j < 2; ++j) {
        int e = (threadIdx.x + j * 256) * 4;
        #pragma unroll
        for (int k = 0; k < 4; ++k)
            if (e + k < nz) prow[e + k] = __float2bfloat16(ev[j * 4 + k] * inv);
    }
}

// ---------------- LayerNorm (eps 1e-5) fp32 -> bf16 ----------------
__global__ __launch_bounds__(256) void k_layernorm(const float* __restrict__ y,
    const float* __restrict__ g, const float* __restrict__ b,
    __hip_bfloat16* __restrict__ yn)
{
    int row = blockIdx.x;
    const float* yr = y + (size_t)row * NE;
    float s = 0.f, s2 = 0.f;
    for (int c = threadIdx.x; c < NE; c += 256) { float v = yr[c]; s += v; s2 += v * v; }
    __shared__ float r1[256], r2[256];
    r1[threadIdx.x] = s; r2[threadIdx.x] = s2; __syncthreads();
    for (int o = 128; o > 0; o >>= 1) {
        if (threadIdx.x < o) { r1[threadIdx.x] += r1[threadIdx.x + o]; r2[threadIdx.x] += r2[threadIdx.x + o]; }
        __syncthreads();
    }
    float mu = r1[0] / NE;
    float var = r2[0] / NE - mu * mu;
    float rs = rsqrtf(var + 1e-5f);
    __hip_bfloat16* o = yn + (size_t)row * NE;
    for (int c = threadIdx.x; c < NE; c += 256)
        o[c] = __float2bfloat16((yr[c] - mu) * rs * g[c] + b[c]);
}

extern "C" void kernel_launch(void* const* d_in, const int* in_sizes, int n_in,
                              void* d_out, int out_size, void* d_ws, size_t ws_size,
                              hipStream_t stream)
{
    const int*   idx  = (const int*)  d_in[0];
    const float* tok  = (const float*)d_in[1];
    const float* pos  = (const float*)d_in[2];
    const float* Wq   = (const float*)d_in[3];
    const float* bq   = (const float*)d_in[4];
    const float* Wk   = (const float*)d_in[5];
    const float* bk   = (const float*)d_in[6];
    const float* Wv   = (const float*)d_in[7];
    const float* bv   = (const float*)d_in[8];
    const float* ln_g = (const float*)d_in[9];
    const float* ln_b = (const float*)d_in[10];
    const float* Wh   = (const float*)d_in[11];
    const float* bh   = (const float*)d_in[12];
    float* out = (float*)d_out;

    const int B = 4, T = 2048, C = 768, V = 50257, Vp = 50432;  // Vp = 197*256

    char* p = (char*)d_ws;
    auto take = [&](size_t bytes) { char* r = p; p += (bytes + 255) & ~(size_t)255; return r; };
    __hip_bfloat16* xb    = (__hip_bfloat16*)take((size_t)B * T * C * 2);
    __hip_bfloat16* wqkvT = (__hip_bfloat16*)take((size_t)3 * C * C * 2);
    float*          bqkv  = (float*)take((size_t)3 * C * 4);
    __hip_bfloat16* qb    = (__hip_bfloat16*)take((size_t)B * T * C * 2);
    __hip_bfloat16* kb    = (__hip_bfloat16*)take((size_t)B * T * C * 2);
    __hip_bfloat16* vb    = (__hip_bfloat16*)take((size_t)B * T * C * 2);
    __hip_bfloat16* vT    = (__hip_bfloat16*)take((size_t)B * T * C * 2);
    float*          att   = (float*)take((size_t)B * T * T * 4);
    __hip_bfloat16* P     = (__hip_bfloat16*)take((size_t)B * T * T * 2);
    float*          y     = (float*)take((size_t)B * T * C * 4);
    __hip_bfloat16* yn    = (__hip_bfloat16*)take((size_t)B * T * C * 2);
    // Wh^T (77.4 MB, Vp rows) reuses the att+P region (100.6 MB) — dead once y exists.
    __hip_bfloat16* whT   = (__hip_bfloat16*)att;

    float scale = 1.0f / sqrtf((float)C);

    k_embed<<<dim3(B * T), 256, 0, stream>>>(idx, tok, pos, xb);
    k_transpose_f32_bf16<<<dim3(24, 24), 256, 0, stream>>>(Wq, wqkvT,             C, C, C);
    k_transpose_f32_bf16<<<dim3(24, 24), 256, 0, stream>>>(Wk, wqkvT + C * C,     C, C, C);
    k_transpose_f32_bf16<<<dim3(24, 24), 256, 0, stream>>>(Wv, wqkvT + 2 * C * C, C, C, C);
    k_pack_bias<<<dim3(9), 256, 0, stream>>>(bq, bk, bv, bqkv);

    // qkv: [8192,768] x [2304,768]^T
    k_gemm<0><<<dim3(18, 64, 1), 256, 0, stream>>>(xb, wqkvT, C, C, C, 0, 0, 0,
        nullptr, 0, 0, bqkv, 1.f, qb, kb, vb);

    k_transpose_bf16<<<dim3(24, 64, B), 256, 0, stream>>>(vb, vT, T, C);

    // att = q k^T / sqrt(C): per batch [2048,768] x [2048,768]^T (causal block skip)
    k_gemm<1><<<dim3(16, 16, B), 256, 0, stream>>>(qb, kb, C, C, C,
        (size_t)T * C, (size_t)T * C, (size_t)T * T, att, T, 0, nullptr, scale,
        nullptr, nullptr, nullptr);

    k_softmax<<<dim3(T, B), 256, 0, stream>>>(att, P, T);

    // y = P v: per batch [2048,2048] x [768,2048]^T, K truncated causally, longest-first
    k_gemm<2><<<dim3(6, 16, B), 256, 0, stream>>>(P, vT, T, T, T,
        (size_t)T * T, (size_t)C * T, (size_t)T * C, y, C, 0, nullptr, 1.f,
        nullptr, nullptr, nullptr);

    // Wh^T after PV so it can overwrite att/P scratch
    k_transpose_f32_bf16<<<dim3(Vp / 32, 24), 256, 0, stream>>>(Wh, whT, C, V, Vp);

    k_layernorm<<<dim3(B * T), 256, 0, stream>>>(y, ln_g, ln_b, yn);

    // logits: [8192,768] x [50432,768]^T -> fp32 d_out; bm-fastest grid (B-panel reuse)
    k_gemm_head<<<dim3(32, Vp / 256), 512, 0, stream>>>(yn, whT, out, bh, V, V);
}

// Round 9
// 1238.660 us; speedup vs baseline: 1.1285x; 1.1285x over previous
//
#include <hip/hip_runtime.h>
#include <hip/hip_bf16.h>
#include <math.h>

typedef __bf16 bf16x8 __attribute__((ext_vector_type(8)));
typedef float  f32x4  __attribute__((ext_vector_type(4)));

#define GAS(p) ((const __attribute__((address_space(1))) void*)(p))
#define LAS(p) ((__attribute__((address_space(3))) void*)(p))

static constexpr int NE = 768;

// ---------------- embed: x = tok_emb[idx] + pos_emb, -> bf16 ----------------
__global__ __launch_bounds__(256) void k_embed(const int* __restrict__ idx,
    const float* __restrict__ tok, const float* __restrict__ pos,
    __hip_bfloat16* __restrict__ xb)
{
    int bt = blockIdx.x;            // 0..8191
    int t  = bt & 2047;
    int token = idx[bt];
    const float* te = tok + (size_t)token * NE;
    const float* pe = pos + (size_t)t * NE;
    __hip_bfloat16* o = xb + (size_t)bt * NE;
    for (int c = threadIdx.x; c < NE; c += 256)
        o[c] = __float2bfloat16(te[c] + pe[c]);
}

// ------------- transpose fp32 [R][C] -> bf16 [outRows][R] (zero-pad) -------------
__global__ __launch_bounds__(256) void k_transpose_f32_bf16(
    const float* __restrict__ in, __hip_bfloat16* __restrict__ out,
    int R, int C, int outRows)
{
    __shared__ float tile[32][33];
    int c0 = blockIdx.x * 32, r0 = blockIdx.y * 32;
    int tx = threadIdx.x & 31, ty = threadIdx.x >> 5;
    #pragma unroll
    for (int i = 0; i < 32; i += 8) {
        int r = r0 + ty + i, c = c0 + tx;
        tile[ty + i][tx] = (r < R && c < C) ? in[(size_t)r * C + c] : 0.f;
    }
    __syncthreads();
    #pragma unroll
    for (int i = 0; i < 32; i += 8) {
        int oc = c0 + ty + i, orr = r0 + tx;
        if (oc < outRows && orr < R)
            out[(size_t)oc * R + orr] = __float2bfloat16(tile[tx][ty + i]);
    }
}

// ------------- batched bf16 transpose: in [z][R][C] -> out [z][C][R] -------------
__global__ __launch_bounds__(256) void k_transpose_bf16(
    const __hip_bfloat16* __restrict__ in, __hip_bfloat16* __restrict__ out,
    int R, int C)
{
    __shared__ __hip_bfloat16 tile[32][33];
    size_t boff = (size_t)blockIdx.z * R * C;
    int c0 = blockIdx.x * 32, r0 = blockIdx.y * 32;
    int tx = threadIdx.x & 31, ty = threadIdx.x >> 5;
    #pragma unroll
    for (int i = 0; i < 32; i += 8)
        tile[ty + i][tx] = in[boff + (size_t)(r0 + ty + i) * C + (c0 + tx)];
    __syncthreads();
    #pragma unroll
    for (int i = 0; i < 32; i += 8)
        out[boff + (size_t)(c0 + ty + i) * R + (r0 + tx)] = tile[tx][ty + i];
}

__global__ __launch_bounds__(256) void k_pack_bias(const float* __restrict__ bq,
    const float* __restrict__ bk, const float* __restrict__ bv, float* __restrict__ o)
{
    int i = blockIdx.x * 256 + threadIdx.x;
    if (i < 768) o[i] = bq[i];
    else if (i < 1536) o[i] = bk[i - 768];
    else if (i < 2304) o[i] = bv[i - 1536];
}

// ---------------- m97-style 128x128 bf16 MFMA GEMM (qkv/att/PV) ----------------
template<int MODE>
__global__ __launch_bounds__(256) void k_gemm(
    const __hip_bfloat16* __restrict__ A, const __hip_bfloat16* __restrict__ Bt,
    int K, int lda, int ldb,
    size_t strideA, size_t strideB, size_t strideC,
    float* __restrict__ outf, int ldc, int ncols,
    const float* __restrict__ bias, float scale,
    __hip_bfloat16* __restrict__ oq, __hip_bfloat16* __restrict__ ok,
    __hip_bfloat16* __restrict__ ov)
{
    int bn = blockIdx.x, bm = blockIdx.y, bz = blockIdx.z;
    if constexpr (MODE == 2) bm = (int)gridDim.y - 1 - bm;   // longest-first dispatch
    if (MODE == 1 && bn > bm) return;   // fully masked causal tile
    __shared__ __align__(16) __hip_bfloat16 As[128 * 32];
    __shared__ __align__(16) __hip_bfloat16 Bs[128 * 32];
    const __hip_bfloat16* Ab = A  + bz * strideA + (size_t)bm * 128 * lda;
    const __hip_bfloat16* Bb = Bt + bz * strideB + (size_t)bn * 128 * ldb;
    int tid = threadIdx.x, w = tid >> 6, lane = tid & 63;
    int wr = w >> 1, wc = w & 1;
    f32x4 acc[4][4] = {};
    int sr = tid >> 2, sc = (tid & 3) * 8;
    int lr = lane & 15, lk = (lane >> 4) * 8;

    const int kend = (MODE == 2) ? (bm + 1) * 128 : K;   // causal K-truncation for PV

    for (int k0 = 0; k0 < kend; k0 += 32) {
        __syncthreads();
        #pragma unroll
        for (int i = 0; i < 2; ++i) {
            __builtin_amdgcn_global_load_lds(GAS(Ab + (size_t)(i * 64 + sr) * lda + k0 + sc),
                                             LAS((char*)As + i * 4096 + w * 1024), 16, 0, 0);
            __builtin_amdgcn_global_load_lds(GAS(Bb + (size_t)(i * 64 + sr) * ldb + k0 + sc),
                                             LAS((char*)Bs + i * 4096 + w * 1024), 16, 0, 0);
        }
        __syncthreads();
        bf16x8 af[4], bfv[4];
        #pragma unroll
        for (int mi = 0; mi < 4; ++mi)
            af[mi] = *(const bf16x8*)(As + (wr * 64 + mi * 16 + lr) * 32 + lk);
        #pragma unroll
        for (int ni = 0; ni < 4; ++ni)
            bfv[ni] = *(const bf16x8*)(Bs + (wc * 64 + ni * 16 + lr) * 32 + lk);
        #pragma unroll
        for (int mi = 0; mi < 4; ++mi)
            #pragma unroll
            for (int ni = 0; ni < 4; ++ni)
                acc[mi][ni] = __builtin_amdgcn_mfma_f32_16x16x32_bf16(af[mi], bfv[ni], acc[mi][ni], 0, 0, 0);
    }

    int r4 = (lane >> 4) * 4;
    #pragma unroll
    for (int mi = 0; mi < 4; ++mi) {
        #pragma unroll
        for (int ni = 0; ni < 4; ++ni) {
            #pragma unroll
            for (int r = 0; r < 4; ++r) {
                int row = bm * 128 + wr * 64 + mi * 16 + r4 + r;
                int col = bn * 128 + wc * 64 + ni * 16 + lr;
                float v = acc[mi][ni][r];
                if constexpr (MODE == 0) {
                    v += bias[col];
                    __hip_bfloat16 h = __float2bfloat16(v);
                    if (col < 768)       oq[(size_t)row * 768 + col]          = h;
                    else if (col < 1536) ok[(size_t)row * 768 + (col - 768)]  = h;
                    else                 ov[(size_t)row * 768 + (col - 1536)] = h;
                } else if constexpr (MODE == 1) {
                    outf[bz * strideC + (size_t)row * ldc + col] = v * scale;
                } else {
                    outf[bz * strideC + (size_t)row * ldc + col] = v;
                }
            }
        }
    }
}

// ================= 256x256 head GEMM — faithful m201 8-phase template =================
// out[8192][V] = A[8192][768]*Bt[50432][768]^T + bias. 8 waves (2M x 4N), BK=64,
// 2 K-tiles per 8-phase iteration (6 iters). A/B in LDS as 2 independently-freed
// 128x64 halves per buffer. Per phase: {ds-read one quadrant's frags,
// stage one half-tile (2 gloads), [vmcnt(4) once per K-tile], barrier, 16 MFMA
// (setprio), barrier}. Stage/wait ledger verified (see phase comments).
__global__ __launch_bounds__(512, 2) void k_gemm_head(
    const __hip_bfloat16* __restrict__ A,   // [8192][768]
    const __hip_bfloat16* __restrict__ Bt,  // [50432][768]
    float* __restrict__ out, const float* __restrict__ bias, int ldc, int ncols)
{
    constexpr int K = 768, NT = K / 64, NI = NT / 2;    // 12 tiles, 6 iters
    __shared__ __align__(16) __hip_bfloat16 As[2][2][128 * 64];  // [buf][half]
    __shared__ __align__(16) __hip_bfloat16 Bs[2][2][128 * 64];

    // bijective XCD remap of fast axis (R6-measured +6%)
    const int Nx = (int)gridDim.x;
    const int qq = Nx >> 3, rr = Nx & 7;
    const int xcd = (int)blockIdx.x & 7, xidx = (int)blockIdx.x >> 3;
    const int bn = (xcd < rr ? xcd * (qq + 1) : rr * (qq + 1) + (xcd - rr) * qq) + xidx;
    const int bm = blockIdx.y;
    const int tid = threadIdx.x;
    const int w = tid >> 6, lane = tid & 63;
    const int wr = w >> 2, wc = w & 3;      // wave = (M-half wr, N-quarter wc)
    const int lr = lane & 15, lu = lane >> 4;

    const int sr = tid >> 3;                // staging row within 64-row chunk
    const int su = (tid & 7) ^ (sr & 7);    // pre-swizzled source 16B unit
    const __hip_bfloat16* Ap = A  + (size_t)(bm * 256) * K;
    const __hip_bfloat16* Bp = Bt + (size_t)(bn * 256) * K;

    f32x4 acc[8][4] = {};
    bf16x8 bq[4][2];

    auto stageAh = [&](int t, int h) {      // A half h (128 rows x 64) -> buf t&1
        #pragma unroll
        for (int l = 0; l < 2; ++l)
            __builtin_amdgcn_global_load_lds(
                GAS(Ap + (size_t)(h * 128 + l * 64 + sr) * K + t * 64 + su * 8),
                LAS(&As[t & 1][h][l * 4096 + tid * 8]), 16, 0, 0);
    };
    auto stageBh = [&](int t, int h) {
        #pragma unroll
        for (int l = 0; l < 2; ++l)
            __builtin_amdgcn_global_load_lds(
                GAS(Bp + (size_t)(h * 128 + l * 64 + sr) * K + t * 64 + su * 8),
                LAS(&Bs[t & 1][h][l * 4096 + tid * 8]), 16, 0, 0);
    };
    auto rdA = [&](int b, int q, int f, int kk) {   // wave wr reads only A-half wr
        int row = q * 32 + f * 16 + lr;
        return *(const bf16x8*)&As[b][wr][row * 64 + (((kk * 4 + lu) ^ (row & 7)) << 3)];
    };
    auto rdB = [&](int b, int n, int kk) {          // wave wc reads only B-half wc>>1
        int row = (wc & 1) * 64 + n * 16 + lr;
        return *(const bf16x8*)&Bs[b][wc >> 1][row * 64 + (((kk * 4 + lu) ^ (row & 7)) << 3)];
    };

#define BAR() asm volatile("s_barrier" ::: "memory")
#define VM4() asm volatile("s_waitcnt vmcnt(4)" ::: "memory")
#define VM0() asm volatile("s_waitcnt vmcnt(0)" ::: "memory")
#define CLUSTER(Q)                                                                                          \
    __builtin_amdgcn_s_setprio(1);                                                                          \
    _Pragma("unroll") for (int n = 0; n < 4; ++n)                                                           \
        acc[2*(Q)+0][n] = __builtin_amdgcn_mfma_f32_16x16x32_bf16(af[0][0], bq[n][0], acc[2*(Q)+0][n], 0, 0, 0); \
    _Pragma("unroll") for (int n = 0; n < 4; ++n)                                                           \
        acc[2*(Q)+1][n] = __builtin_amdgcn_mfma_f32_16x16x32_bf16(af[1][0], bq[n][0], acc[2*(Q)+1][n], 0, 0, 0); \
    _Pragma("unroll") for (int n = 0; n < 4; ++n)                                                           \
        acc[2*(Q)+0][n] = __builtin_amdgcn_mfma_f32_16x16x32_bf16(af[0][1], bq[n][1], acc[2*(Q)+0][n], 0, 0, 0); \
    _Pragma("unroll") for (int n = 0; n < 4; ++n)                                                           \
        acc[2*(Q)+1][n] = __builtin_amdgcn_mfma_f32_16x16x32_bf16(af[1][1], bq[n][1], acc[2*(Q)+1][n], 0, 0, 0); \
    __builtin_amdgcn_s_setprio(0);
#define PH(B_, Q_, STAGE, VM)                                                   \
    {   bf16x8 af[2][2];                                                        \
        _Pragma("unroll") for (int f = 0; f < 2; ++f) {                         \
            af[f][0] = rdA(B_, Q_, f, 0); af[f][1] = rdA(B_, Q_, f, 1); }       \
        STAGE                                                                   \
        VM                                                                      \
        BAR();                                                                  \
        CLUSTER(Q_)                                                             \
        BAR(); }

    // prologue: B(0),A(0),B(1) = 12 loads; full drain before first reads
    stageBh(0, 0); stageBh(0, 1);
    stageAh(0, 0); stageAh(0, 1);
    stageBh(1, 0); stageBh(1, 1);
    VM0();
    BAR();

    for (int i = 0; i < NI; ++i) {
        const int t0 = 2 * i, t1 = 2 * i + 1;
        const bool full = (i + 1 < NI);
        // ---- tile t0 (buf 0): B reads to regs; stage A(t1) (A-buf1 freed prev ph7) ----
        #pragma unroll
        for (int n = 0; n < 4; ++n) { bq[n][0] = rdB(0, n, 0); bq[n][1] = rdB(0, n, 1); }
        PH(0, 0, stageAh(t1, 0); stageAh(t1, 1);, )
        PH(0, 1, if (full) { stageBh(t0 + 2, 0); }, )   // B-buf0 freed at ph0
        PH(0, 2, if (full) { stageBh(t0 + 2, 1); }, )
        PH(0, 3, , if (full) { VM4(); } else { VM0(); })   // gate tile t1's data
        // ---- tile t1 (buf 1) ----
        #pragma unroll
        for (int n = 0; n < 4; ++n) { bq[n][0] = rdB(1, n, 0); bq[n][1] = rdB(1, n, 1); }
        PH(1, 0, if (full) { stageAh(t0 + 2, 0); }, )   // A-buf0 freed at ph3
        PH(1, 1, if (full) { stageAh(t0 + 2, 1); }, )
        PH(1, 2, if (full) { stageBh(t1 + 2, 0); }, )   // B-buf1 freed at ph4
        PH(1, 3, if (full) { stageBh(t1 + 2, 1); }, if (full) { VM4(); } else { VM0(); })  // gate next t0
    }
#undef PH
#undef CLUSTER
#undef VM0
#undef VM4
#undef BAR

    // epilogue: C-write with bias, col-bounded (acc[m][n], m = 2q+f, row = wr*128+m*16)
    const int r4 = lu * 4;
    #pragma unroll
    for (int m = 0; m < 8; ++m) {
        #pragma unroll
        for (int n = 0; n < 4; ++n) {
            int col = bn * 256 + wc * 64 + n * 16 + lr;
            if (col < ncols) {
                float bv_ = bias[col];
                #pragma unroll
                for (int r = 0; r < 4; ++r) {
                    int row = bm * 256 + wr * 128 + m * 16 + r4 + r;
                    out[(size_t)row * ldc + col] = acc[m][n][r] + bv_;
                }
            }
        }
    }
}

// ---------------- causal softmax: float4 loads, __expf, zero-fill to 128-boundary ----------------
__global__ __launch_bounds__(256) void k_softmax(const float* __restrict__ att,
    __hip_bfloat16* __restrict__ P, int T)
{
    int t = blockIdx.x, b = blockIdx.y;
    const float* row = att + ((size_t)b * T + t) * T;
    __hip_bfloat16* prow = P + ((size_t)b * T + t) * T;
    const int n = t + 1;
    const int nz = ((t >> 7) + 1) << 7;     // PV (truncated) reads only cols < nz
    __shared__ float red[256];
    float4 v[2];
    float mx = -1e30f;
    #pragma unroll
    for (int j = 0; j < 2; ++j) {
        int e = (threadIdx.x + j * 256) * 4;
        v[j] = *(const float4*)(row + e);
        #pragma unroll
        for (int k = 0; k < 4; ++k)
            if (e + k < n) mx = fmaxf(mx, ((const float*)&v[j])[k]);
    }
    red[threadIdx.x] = mx; __syncthreads();
    for (int o = 128; o > 0; o >>= 1) {
        if (threadIdx.x < o) red[threadIdx.x] = fmaxf(red[threadIdx.x], red[threadIdx.x + o]);
        __syncthreads();
    }
    mx = red[0]; __syncthreads();
    float ev[8];
    float sum = 0.f;
    #pragma unroll
    for (int j = 0; j < 2; ++j) {
        int e = (threadIdx.x + j * 256) * 4;
        #pragma unroll
        for (int k = 0; k < 4; ++k) {
            float x = ((const float*)&v[j])[k];
            float ex = (e + k < n) ? __expf(x - mx) : 0.f;
            ev[j * 4 + k] = ex;
            sum += ex;
        }
    }
    red[threadIdx.x] = sum; __syncthreads();
    for (int o = 128; o > 0; o >>= 1) {
        if (threadIdx.x < o) red[threadIdx.x] += red[threadIdx.x + o];
        __syncthreads();
    }
    float inv = 1.f / red[0];
    #pragma unroll
    for (int j = 0; j < 2; ++j) {
        int e = (threadIdx.x + j * 256) * 4;
        #pragma unroll
        for (int k = 0; k < 4; ++k)
            if (e + k < nz) prow[e + k] = __float2bfloat16(ev[j * 4 + k] * inv);
    }
}

// ---------------- LayerNorm (eps 1e-5) fp32 -> bf16 ----------------
__global__ __launch_bounds__(256) void k_layernorm(const float* __restrict__ y,
    const float* __restrict__ g, const float* __restrict__ b,
    __hip_bfloat16* __restrict__ yn)
{
    int row = blockIdx.x;
    const float* yr = y + (size_t)row * NE;
    float s = 0.f, s2 = 0.f;
    for (int c = threadIdx.x; c < NE; c += 256) { float v = yr[c]; s += v; s2 += v * v; }
    __shared__ float r1[256], r2[256];
    r1[threadIdx.x] = s; r2[threadIdx.x] = s2; __syncthreads();
    for (int o = 128; o > 0; o >>= 1) {
        if (threadIdx.x < o) { r1[threadIdx.x] += r1[threadIdx.x + o]; r2[threadIdx.x] += r2[threadIdx.x + o]; }
        __syncthreads();
    }
    float mu = r1[0] / NE;
    float var = r2[0] / NE - mu * mu;
    float rs = rsqrtf(var + 1e-5f);
    __hip_bfloat16* o = yn + (size_t)row * NE;
    for (int c = threadIdx.x; c < NE; c += 256)
        o[c] = __float2bfloat16((yr[c] - mu) * rs * g[c] + b[c]);
}

extern "C" void kernel_launch(void* const* d_in, const int* in_sizes, int n_in,
                              void* d_out, int out_size, void* d_ws, size_t ws_size,
                              hipStream_t stream)
{
    const int*   idx  = (const int*)  d_in[0];
    const float* tok  = (const float*)d_in[1];
    const float* pos  = (const float*)d_in[2];
    const float* Wq   = (const float*)d_in[3];
    const float* bq   = (const float*)d_in[4];
    const float* Wk   = (const float*)d_in[5];
    const float* bk   = (const float*)d_in[6];
    const float* Wv   = (const float*)d_in[7];
    const float* bv   = (const float*)d_in[8];
    const float* ln_g = (const float*)d_in[9];
    const float* ln_b = (const float*)d_in[10];
    const float* Wh   = (const float*)d_in[11];
    const float* bh   = (const float*)d_in[12];
    float* out = (float*)d_out;

    const int B = 4, T = 2048, C = 768, V = 50257, Vp = 50432;  // Vp = 197*256

    char* p = (char*)d_ws;
    auto take = [&](size_t bytes) { char* r = p; p += (bytes + 255) & ~(size_t)255; return r; };
    __hip_bfloat16* xb    = (__hip_bfloat16*)take((size_t)B * T * C * 2);
    __hip_bfloat16* wqkvT = (__hip_bfloat16*)take((size_t)3 * C * C * 2);
    float*          bqkv  = (float*)take((size_t)3 * C * 4);
    __hip_bfloat16* qb    = (__hip_bfloat16*)take((size_t)B * T * C * 2);
    __hip_bfloat16* kb    = (__hip_bfloat16*)take((size_t)B * T * C * 2);
    __hip_bfloat16* vb    = (__hip_bfloat16*)take((size_t)B * T * C * 2);
    __hip_bfloat16* vT    = (__hip_bfloat16*)take((size_t)B * T * C * 2);
    float*          att   = (float*)take((size_t)B * T * T * 4);
    __hip_bfloat16* P     = (__hip_bfloat16*)take((size_t)B * T * T * 2);
    float*          y     = (float*)take((size_t)B * T * C * 4);
    __hip_bfloat16* yn    = (__hip_bfloat16*)take((size_t)B * T * C * 2);
    // Wh^T (77.4 MB, Vp rows) reuses the att+P region (100.6 MB) — dead once y exists.
    __hip_bfloat16* whT   = (__hip_bfloat16*)att;

    float scale = 1.0f / sqrtf((float)C);

    k_embed<<<dim3(B * T), 256, 0, stream>>>(idx, tok, pos, xb);
    k_transpose_f32_bf16<<<dim3(24, 24), 256, 0, stream>>>(Wq, wqkvT,             C, C, C);
    k_transpose_f32_bf16<<<dim3(24, 24), 256, 0, stream>>>(Wk, wqkvT + C * C,     C, C, C);
    k_transpose_f32_bf16<<<dim3(24, 24), 256, 0, stream>>>(Wv, wqkvT + 2 * C * C, C, C, C);
    k_pack_bias<<<dim3(9), 256, 0, stream>>>(bq, bk, bv, bqkv);

    // qkv: [8192,768] x [2304,768]^T
    k_gemm<0><<<dim3(18, 64, 1), 256, 0, stream>>>(xb, wqkvT, C, C, C, 0, 0, 0,
        nullptr, 0, 0, bqkv, 1.f, qb, kb, vb);

    k_transpose_bf16<<<dim3(24, 64, B), 256, 0, stream>>>(vb, vT, T, C);

    // att = q k^T / sqrt(C): per batch [2048,768] x [2048,768]^T (causal block skip)
    k_gemm<1><<<dim3(16, 16, B), 256, 0, stream>>>(qb, kb, C, C, C,
        (size_t)T * C, (size_t)T * C, (size_t)T * T, att, T, 0, nullptr, scale,
        nullptr, nullptr, nullptr);

    k_softmax<<<dim3(T, B), 256, 0, stream>>>(att, P, T);

    // y = P v: per batch [2048,2048] x [768,2048]^T, K truncated causally, longest-first
    k_gemm<2><<<dim3(6, 16, B), 256, 0, stream>>>(P, vT, T, T, T,
        (size_t)T * T, (size_t)C * T, (size_t)T * C, y, C, 0, nullptr, 1.f,
        nullptr, nullptr, nullptr);

    // Wh^T after PV so it can overwrite att/P scratch
    k_transpose_f32_bf16<<<dim3(Vp / 32, 24), 256, 0, stream>>>(Wh, whT, C, V, Vp);

    k_layernorm<<<dim3(B * T), 256, 0, stream>>>(y, ln_g, ln_b, yn);

    // logits: [8192,768] x [50432,768]^T -> fp32 d_out; m201 8-phase template + XCD swizzle
    k_gemm_head<<<dim3(Vp / 256, 32), 512, 0, stream>>>(yn, whT, out, bh, V, V);
}